// Round 2
// baseline (5970.219 us; speedup 1.0000x reference)
//
#include <hip/hip_runtime.h>
#include <stdint.h>

// LSTM-VAE for MI355X (gfx950).  B=512, T=256, CIN=128, H=256, COUT=64.
//
// Round-1 redesign:
//  - NO giant gate-precompute buffer (r0 needed ~711MB ws -> suspected fault).
//    ws now ~142MB.
//  - Recurrences are persistent gate-split kernels: each WG owns a slice of
//    gate rows with its weight fragments RESIDENT IN REGISTERS (loaded once,
//    reused all 256 steps). h is exchanged between the 8 WGs of a batch-tile
//    through global memory with device-scope coherent stores + per-step
//    arrival counters (double-buffered to avoid WAR).
//  - 96KB LDS per WG forces 1 WG/CU; encoder grid = 256 WGs = #CUs, so all
//    WGs are co-resident (spin-sync safe).
//  - Only mfma_f32_16x16x32_bf16 (guide-verified short8 signature) is used.

typedef __attribute__((ext_vector_type(8)))  short  short8;
typedef __attribute__((ext_vector_type(4)))  float  f32x4;
typedef __attribute__((ext_vector_type(2)))  float  f32x2;
typedef __attribute__((ext_vector_type(4)))  unsigned short u16x4;

static __device__ __forceinline__ float bf2f(unsigned short u){
  union{unsigned int i; float f;} v; v.i = ((unsigned int)u)<<16; return v.f;
}
static __device__ __forceinline__ unsigned short f2bf(float f){
  union{float f; unsigned int i;} v; v.f=f;
  return (unsigned short)((v.i + 0x7fffu + ((v.i>>16)&1u))>>16);
}
static __device__ __forceinline__ float sigm(float x){ return 1.f/(1.f+__expf(-x)); }
static __device__ __forceinline__ float tanh_(float x){ return 2.f/(1.f+__expf(-2.f*x)) - 1.f; }

#define MFMA(a,b,c) __builtin_amdgcn_mfma_f32_16x16x32_bf16((a),(b),(c),0,0,0)

// gate-row permutation: n' = s*32 + mi*16 + lg*4 + g  with hu = s*8 + lg*2 + mi
// (lane lg holds hidden units {s*8+lg*2, +1} -> 4 gates land in one lane's
//  D-fragment (rr=g), and the lane's two h values are ADJACENT hu -> dword pack)
static __device__ __forceinline__ int permn(int np){
  int s = np>>5, mi = (np>>4)&1, lg = (np>>2)&3, g = np&3;
  int hu = s*8 + lg*2 + mi;
  return g*256 + hu;
}

// ---------------- tiny prep kernels ----------------

__global__ void k_memz(int* p, int n){
  int i = blockIdx.x*blockDim.x + threadIdx.x;
  if (i < n) p[i] = 0;
}

__global__ void k_cvt4(const float* __restrict__ s, unsigned short* __restrict__ d, long n4){
  for (long i = (long)blockIdx.x*blockDim.x + threadIdx.x; i < n4; i += (long)gridDim.x*blockDim.x){
    f32x4 v = *(const f32x4*)(s + i*4);
    u16x4 u; u[0]=f2bf(v[0]); u[1]=f2bf(v[1]); u[2]=f2bf(v[2]); u[3]=f2bf(v[3]);
    *(u16x4*)(d + i*4) = u;
  }
}

// Wenc[chain][n'][k] : k<256 -> Wih[n][k], k>=256 -> Whh[n][k-256]; benc[chain][n']
__global__ void k_prepenc(const float* __restrict__ Wihf, const float* __restrict__ Whhf,
                          const float* __restrict__ bf_,
                          const float* __restrict__ Wihb, const float* __restrict__ Whhb,
                          const float* __restrict__ bb_,
                          unsigned short* __restrict__ Wenc, float* __restrict__ benc){
  for (long i = (long)blockIdx.x*blockDim.x + threadIdx.x; i < 2L*1024*512; i += (long)gridDim.x*blockDim.x){
    int k  = (int)(i & 511);
    int np = (int)((i >> 9) & 1023);
    int ch = (int)(i >> 19);
    int n  = permn(np);
    const float* Wih = ch ? Wihb : Wihf;
    const float* Whh = ch ? Whhb : Whhf;
    float v = (k < 256) ? Wih[n*256 + k] : Whh[n*256 + (k-256)];
    Wenc[i] = f2bf(v);
    if (k == 0) benc[ch*1024 + np] = ch ? bb_[n] : bf_[n];
  }
}

// Wsum[n'][k] = Wih_d+Whh_d (inp==h for t>=1); W0r[n'][k] = Whh_d; biasd[n'];
// Wdecb[r][k] = W_dec natural rows (bf16)
__global__ void k_prepdec(const float* __restrict__ Wihd, const float* __restrict__ Whhd,
                          const float* __restrict__ bd, const float* __restrict__ Wdec,
                          unsigned short* __restrict__ Wsum, unsigned short* __restrict__ W0r,
                          float* __restrict__ biasd, unsigned short* __restrict__ Wdecb){
  const long N1 = 1024L*256;
  for (long i = (long)blockIdx.x*blockDim.x + threadIdx.x; i < N1 + 128L*256; i += (long)gridDim.x*blockDim.x){
    if (i < N1){
      int k = (int)(i & 255), np = (int)(i >> 8);
      int n = permn(np);
      float wh = Whhd[n*256 + k];
      Wsum[i] = f2bf(Wihd[n*256 + k] + wh);
      W0r[i]  = f2bf(wh);
      if (k == 0) biasd[np] = bd[n];
    } else {
      long j = i - N1;
      Wdecb[j] = f2bf(Wdec[j]);
    }
  }
}

// ---------------- GEMM: C[M,N] = A_f32[M,K] @ Bt_bf16[N,K]^T + bias ----------------
// 128x128 tile, K-chunks of 64, reg-staged (fp32 A converted on the fly),
// XOR-swizzled LDS (T2) to kill the 16-way row-stride conflicts.
__global__ __launch_bounds__(256, 2) void k_gemmA32(
    const float* __restrict__ A, const unsigned short* __restrict__ Bt,
    void* __restrict__ Cout, const float* __restrict__ bias,
    int M, int N, int K, int outf32)
{
  __shared__ unsigned short As[128*64];
  __shared__ unsigned short Bs[128*64];
  const int tid = threadIdx.x, lane = tid & 63, wid = tid >> 6;
  const int lg = lane >> 4, r15 = lane & 15;
  const long mbase = (long)blockIdx.y * 128;
  const long nbase = (long)blockIdx.x * 128;
  f32x4 acc[4][4];
#pragma unroll
  for (int i=0;i<4;i++)
#pragma unroll
    for (int j=0;j<4;j++) acc[i][j] = (f32x4)(0.f);
  const int wrow = (wid>>1)*64, wcol = (wid&1)*64;

  for (int kc = 0; kc < K; kc += 64){
    {
      const int col4 = (tid&15)*4, rowb = tid>>4;
#pragma unroll
      for (int i=0;i<8;i++){
        int row = rowb + 16*i;
        f32x4 v = *(const f32x4*)(A + (mbase+row)*(long)K + kc + col4);
        u16x4 u; u[0]=f2bf(v[0]); u[1]=f2bf(v[1]); u[2]=f2bf(v[2]); u[3]=f2bf(v[3]);
        int byte = row*128 + ((col4*2) ^ ((row&7)<<4));
        *(u16x4*)((char*)As + byte) = u;
      }
      const int kq = tid&7, rowb2 = tid>>3;
#pragma unroll
      for (int i=0;i<4;i++){
        int row = rowb2 + 32*i;
        short8 v = *(const short8*)(Bt + (nbase+row)*(long)K + kc + kq*8);
        int byte = row*128 + ((kq*16) ^ ((row&7)<<4));
        *(short8*)((char*)Bs + byte) = v;
      }
    }
    __syncthreads();
#pragma unroll
    for (int ks=0; ks<2; ++ks){
      short8 a[4], b[4];
#pragma unroll
      for (int mi=0; mi<4; ++mi){
        int row = wrow + mi*16 + r15;
        int byte = row*128 + ((ks*64 + lg*16) ^ ((row&7)<<4));
        a[mi] = *(const short8*)((char*)As + byte);
      }
#pragma unroll
      for (int ni=0; ni<4; ++ni){
        int row = wcol + ni*16 + r15;
        int byte = row*128 + ((ks*64 + lg*16) ^ ((row&7)<<4));
        b[ni] = *(const short8*)((char*)Bs + byte);
      }
#pragma unroll
      for (int mi=0; mi<4; ++mi)
#pragma unroll
        for (int ni=0; ni<4; ++ni)
          acc[mi][ni] = MFMA(a[mi], b[ni], acc[mi][ni]);
    }
    __syncthreads();
  }
#pragma unroll
  for (int ni=0; ni<4; ++ni){
    long col = nbase + wcol + ni*16 + r15;
    float bv = bias[col];
#pragma unroll
    for (int mi=0; mi<4; ++mi)
#pragma unroll
      for (int rr=0; rr<4; ++rr){
        long row = mbase + wrow + mi*16 + lg*4 + rr;
        float val = acc[mi][ni][rr] + bv;
        if (outf32) ((float*)Cout)[row*N + col] = val;
        else        ((unsigned short*)Cout)[row*N + col] = f2bf(val);
      }
  }
}

// ---------------- BatchNorm ----------------

__global__ void k_bnstats(const unsigned short* __restrict__ hb, float* __restrict__ bn){
  __shared__ float sred[8][256];
  __shared__ float qred[8][256];
  const int tid = threadIdx.x, kq = tid&31, rw = tid>>5;
  float s[8], qq[8];
#pragma unroll
  for (int j=0;j<8;j++){ s[j]=0.f; qq[j]=0.f; }
  const long base = (long)blockIdx.x * 512;
  for (int i=0;i<64;i++){
    long row = base + rw + 8L*i;
    short8 v = *(const short8*)(hb + row*256 + kq*8);
#pragma unroll
    for (int j=0;j<8;j++){ float f = bf2f(((unsigned short*)&v)[j]); s[j]+=f; qq[j]+=f*f; }
  }
#pragma unroll
  for (int j=0;j<8;j++){ sred[rw][kq*8+j]=s[j]; qred[rw][kq*8+j]=qq[j]; }
  __syncthreads();
  if (tid < 256){
    float ts=0.f, tq=0.f;
#pragma unroll
    for (int r=0;r<8;r++){ ts += sred[r][tid]; tq += qred[r][tid]; }
    atomicAdd(&bn[tid], ts);
    atomicAdd(&bn[256+tid], tq);
  }
}

__global__ void k_bnab(const float* __restrict__ bn, const float* __restrict__ gamma,
                       const float* __restrict__ beta, float* __restrict__ ab){
  const int j = threadIdx.x;
  const float mean = bn[j] * (1.f/131072.f);
  const float var  = bn[256+j] * (1.f/131072.f) - mean*mean;
  const float a = gamma[j] * rsqrtf(var + 1e-5f);
  ab[j] = a;
  ab[256+j] = beta[j] - mean*a;
}

// seq[t][b][h] = leakyrelu(a*h_b[b][t][h]+b2)  (bf16, [T,B,H])
__global__ void k_bnapply(const unsigned short* __restrict__ hb, const float* __restrict__ ab,
                          unsigned short* __restrict__ seq){
  const int tid = threadIdx.x, kq = tid&31, ro = tid>>5;
  float av[8], bv[8];
#pragma unroll
  for (int j=0;j<8;j++){ av[j]=ab[kq*8+j]; bv[j]=ab[256+kq*8+j]; }
  const long r0 = (long)blockIdx.x * 64;
  for (int i=0;i<8;i++){
    long row = r0 + ro + 8L*i;
    short8 v = *(const short8*)(hb + row*256 + kq*8);
    short8 u;
#pragma unroll
    for (int j=0;j<8;j++){
      float f = bf2f(((unsigned short*)&v)[j])*av[j] + bv[j];
      f = f > 0.f ? f : 0.2f*f;
      ((unsigned short*)&u)[j] = f2bf(f);
    }
    long b = row >> 8, t = row & 255;
    *(short8*)(seq + (t*512 + b)*256 + kq*8) = u;
  }
}

// ---------------- encoder recurrence ----------------
// 256 WGs x 256 thr. WG=(chain, m-tile of 32 batch, q gate slice of 128 rows).
// Weight A-fragments resident in registers (a[2][16], 128 VGPR). h exchanged
// via coherent global stores + per-(m,t) counters, double-buffered.
__global__ __launch_bounds__(256, 1) void k_enc(
    const unsigned short* __restrict__ seqb, const unsigned short* __restrict__ Wenc,
    const float* __restrict__ benc, unsigned short* __restrict__ Hx,
    int* __restrict__ flags, float* __restrict__ hF, float* __restrict__ cF,
    float* __restrict__ hB, float* __restrict__ cB)
{
  __shared__ unsigned short stage[49152];   // uses [64 kq][32 b][8] = 32KB; rest pads LDS to force 1 WG/CU
  const int tid = threadIdx.x, lane = tid & 63, w = tid >> 6;
  const int lg = (lane>>4)&3, r15 = lane & 15;
  const int bid = blockIdx.x, chain = bid>>7, m = (bid>>3)&15, q = bid&7;
  const int mbase = m*32;

  const unsigned short* Wp = Wenc + ((long)chain*1024 + q*128 + w*32)*512;
  short8 a[2][16];
#pragma unroll
  for (int mi=0; mi<2; ++mi)
#pragma unroll
    for (int ks=0; ks<16; ++ks)
      a[mi][ks] = *(const short8*)(Wp + (long)(mi*16 + r15)*512 + ks*32 + lg*8);
  f32x4 bias[2];
#pragma unroll
  for (int mi=0; mi<2; ++mi)
    bias[mi] = *(const f32x4*)(benc + chain*1024 + q*128 + w*32 + mi*16 + lg*4);

  float c[2][2];
  c[0][0]=0.f; c[0][1]=0.f; c[1][0]=0.f; c[1][1]=0.f;
  float* hOut = chain ? hB : hF;
  float* cOut = chain ? cB : cF;
  int* flg = flags + (chain*16 + m)*256;
  unsigned short* HxC = Hx + (long)chain*2*16*32*256;
  const int sb = tid&31, sk = tid>>5;
  const int hu0 = (q*4 + w)*8 + lg*2;

  short8 xreg[4], hreg[4];
  {
    long trow = chain ? 255 : 0;
#pragma unroll
    for (int j=0;j<4;j++)
      xreg[j] = *(const short8*)(seqb + (trow*512 + mbase + sb)*256 + (sk + j*8)*8);
  }

  for (int t=0; t<256; ++t){
    // stage x_t
#pragma unroll
    for (int j=0;j<4;j++)
      *(short8*)&stage[((sk + j*8)*32 + sb)*8] = xreg[j];
    __syncthreads();                               // B1: x visible
    if (t < 255){
      long trow = chain ? (long)(254 - t) : (long)(t + 1);
#pragma unroll
      for (int j=0;j<4;j++)
        xreg[j] = *(const short8*)(seqb + (trow*512 + mbase + sb)*256 + (sk + j*8)*8);
    }
    if (t > 0){
      if (tid == 0){
        while (__hip_atomic_load(flg + t - 1, __ATOMIC_RELAXED, __HIP_MEMORY_SCOPE_AGENT) < 8)
          __builtin_amdgcn_s_sleep(1);
        __threadfence();                           // acquire: invalidate stale L1/L2
      }
      __syncthreads();                             // B2
      const unsigned short* hsrc = HxC + ((long)((t-1)&1)*16 + m)*32*256;
#pragma unroll
      for (int j=0;j<4;j++)
        hreg[j] = *(const short8*)(hsrc + (long)sb*256 + (sk + j*8)*8);
    }
    // x-part MFMAs (overlap h-exchange latency)
    f32x4 acc[2][2];
    acc[0][0]=bias[0]; acc[0][1]=bias[0]; acc[1][0]=bias[1]; acc[1][1]=bias[1];
#pragma unroll
    for (int ks=0; ks<8; ++ks){
      short8 b0 = *(const short8*)&stage[((ks*4+lg)*32 + r15)*8];
      short8 b1 = *(const short8*)&stage[((ks*4+lg)*32 + 16 + r15)*8];
      acc[0][0] = MFMA(a[0][ks], b0, acc[0][0]);
      acc[1][0] = MFMA(a[1][ks], b0, acc[1][0]);
      acc[0][1] = MFMA(a[0][ks], b1, acc[0][1]);
      acc[1][1] = MFMA(a[1][ks], b1, acc[1][1]);
    }
    if (t > 0){
#pragma unroll
      for (int j=0;j<4;j++)
        *(short8*)&stage[((32 + sk + j*8)*32 + sb)*8] = hreg[j];
      __syncthreads();                             // B3: h visible
#pragma unroll
      for (int ks=8; ks<16; ++ks){
        short8 b0 = *(const short8*)&stage[((ks*4+lg)*32 + r15)*8];
        short8 b1 = *(const short8*)&stage[((ks*4+lg)*32 + 16 + r15)*8];
        acc[0][0] = MFMA(a[0][ks], b0, acc[0][0]);
        acc[1][0] = MFMA(a[1][ks], b0, acc[1][0]);
        acc[0][1] = MFMA(a[0][ks], b1, acc[0][1]);
        acc[1][1] = MFMA(a[1][ks], b1, acc[1][1]);
      }
    }
    // cell update (lane: hu0+mi for batch nj*16+r15; rr = gate i,f,g,o)
    float hn[2][2];
#pragma unroll
    for (int mi=0; mi<2; ++mi)
#pragma unroll
      for (int nj=0; nj<2; ++nj){
        float iv = sigm(acc[mi][nj][0]);
        float fv = sigm(acc[mi][nj][1]);
        float gv = tanh_(acc[mi][nj][2]);
        float ov = sigm(acc[mi][nj][3]);
        float cn = fv*c[mi][nj] + iv*gv;
        c[mi][nj] = cn;
        hn[mi][nj] = ov*tanh_(cn);
      }
    if (t < 255){
      unsigned short* dst = HxC + ((long)(t&1)*16 + m)*32*256;
#pragma unroll
      for (int nj=0; nj<2; ++nj){
        unsigned int pk = (unsigned int)f2bf(hn[0][nj]) | ((unsigned int)f2bf(hn[1][nj]) << 16);
        __hip_atomic_store((unsigned int*)(dst + (long)(nj*16 + r15)*256 + hu0), pk,
                           __ATOMIC_RELAXED, __HIP_MEMORY_SCOPE_AGENT);
      }
      __syncthreads();                             // B4: drain stores
      if (tid == 0)
        __hip_atomic_fetch_add(flg + t, 1, __ATOMIC_RELEASE, __HIP_MEMORY_SCOPE_AGENT);
    } else {
#pragma unroll
      for (int nj=0; nj<2; ++nj){
        long b = mbase + nj*16 + r15;
        f32x2 hv; hv[0]=hn[0][nj]; hv[1]=hn[1][nj];
        f32x2 cv; cv[0]=c[0][nj];  cv[1]=c[1][nj];
        *(f32x2*)(hOut + b*256 + hu0) = hv;
        *(f32x2*)(cOut + b*256 + hu0) = cv;
      }
    }
  }
}

// ---------------- latent head ----------------
__global__ void k_mid(
    const float* __restrict__ hF, const float* __restrict__ cF,
    const float* __restrict__ hB, const float* __restrict__ cB,
    const float* __restrict__ eps,
    const float* __restrict__ Wmu, const float* __restrict__ bmu,
    const float* __restrict__ Wlv, const float* __restrict__ blv,
    const float* __restrict__ Wso, const float* __restrict__ bso,
    float* __restrict__ z, float* __restrict__ mu, float* __restrict__ stdo,
    float* __restrict__ so, float* __restrict__ c0)
{
  __shared__ float code[256];
  __shared__ float zsh[256];
  const int b = blockIdx.x, j = threadIdx.x;
  const long o = (long)b*256 + j;
  code[j] = hF[o] + hB[o];
  c0[o] = cF[o] + cB[o];
  __syncthreads();
  float sm = bmu[j], sl = blv[j];
  for (int k=0;k<256;k++){
    float cv = code[k];
    sm += cv * Wmu[j*256 + k];
    sl += cv * Wlv[j*256 + k];
  }
  float st = __expf(0.5f*sl);
  float zz = sm + st*eps[o];
  mu[o]=sm; stdo[o]=st; z[o]=zz;
  zsh[j]=zz;
  __syncthreads();
  if (j < 64){
    float s = bso[j];
    for (int k=0;k<256;k++) s += zsh[k]*Wso[j*256 + k];
    so[(long)b*64 + j] = s;
  }
}

// ---------------- decoder recurrence ----------------
// 128 WGs x 320 thr (4 gate waves + 1 y wave). K=256 (Wih+Whh since inp==h).
// t=0 gates come from precomputed pre0 = Whh@z + b (no MFMA). y_t computed at
// iter t+1 from the freshly staged h^(t+1); extra epilogue for y_255.
__global__ __launch_bounds__(320, 1) void k_dec(
    const unsigned short* __restrict__ Wsum, const unsigned short* __restrict__ Wdecb,
    const float* __restrict__ biasd, const float* __restrict__ bdec,
    const float* __restrict__ pre0, const float* __restrict__ c0,
    unsigned short* __restrict__ Hx, int* __restrict__ flags, float* __restrict__ out)
{
  __shared__ unsigned short stage[49152];   // uses [32 kq][32 b][8] = 16KB
  const int tid = threadIdx.x, lane = tid & 63, w = tid >> 6;
  const int lg = (lane>>4)&3, r15 = lane & 15;
  const int m = blockIdx.x>>3, q = blockIdx.x&7, mbase = m*32;
  int* flg = flags + m*256;
  const int sb = tid&31, sk = tid>>5;
  const int hu0 = (q*4 + w)*8 + lg*2;

  short8 a[2][8];
  f32x4 bias[2];
  float c[2][2];
  short8 ad[8];
  f32x4 ybias;
  if (w < 4){
    const unsigned short* Wp = Wsum + (long)(q*128 + w*32)*256;
#pragma unroll
    for (int mi=0; mi<2; ++mi)
#pragma unroll
      for (int ks=0; ks<8; ++ks)
        a[mi][ks] = *(const short8*)(Wp + (long)(mi*16 + r15)*256 + ks*32 + lg*8);
#pragma unroll
    for (int mi=0; mi<2; ++mi)
      bias[mi] = *(const f32x4*)(biasd + q*128 + w*32 + mi*16 + lg*4);
#pragma unroll
    for (int nj=0; nj<2; ++nj){
      f32x2 cc = *(const f32x2*)(c0 + (long)(mbase + nj*16 + r15)*256 + hu0);
      c[0][nj]=cc[0]; c[1][nj]=cc[1];
    }
  } else {
#pragma unroll
    for (int ks=0; ks<8; ++ks)
      ad[ks] = *(const short8*)(Wdecb + (long)(q*16 + r15)*256 + ks*32 + lg*8);
    ybias = *(const f32x4*)(bdec + q*16 + lg*4);
  }

  short8 hreg[4];
  for (int t=0; t<256; ++t){
    if (t > 0){
      if (tid == 0){
        while (__hip_atomic_load(flg + t - 1, __ATOMIC_RELAXED, __HIP_MEMORY_SCOPE_AGENT) < 8)
          __builtin_amdgcn_s_sleep(1);
        __threadfence();
      }
      __syncthreads();                             // D1
      if (tid < 256){
        const unsigned short* hsrc = Hx + ((long)((t-1)&1)*16 + m)*32*256;
#pragma unroll
        for (int j=0;j<4;j++)
          hreg[j] = *(const short8*)(hsrc + (long)sb*256 + (sk + j*8)*8);
#pragma unroll
        for (int j=0;j<4;j++)
          *(short8*)&stage[((sk + j*8)*32 + sb)*8] = hreg[j];
      }
      __syncthreads();                             // D2: h^(t) staged
    }
    if (w < 4){
      f32x4 acc[2][2];
      if (t == 0){
#pragma unroll
        for (int mi=0; mi<2; ++mi)
#pragma unroll
          for (int nj=0; nj<2; ++nj)
            acc[mi][nj] = *(const f32x4*)(pre0 + (long)(mbase + nj*16 + r15)*1024 + q*128 + w*32 + mi*16 + lg*4);
      } else {
        acc[0][0]=bias[0]; acc[0][1]=bias[0]; acc[1][0]=bias[1]; acc[1][1]=bias[1];
#pragma unroll
        for (int ks=0; ks<8; ++ks){
          short8 b0 = *(const short8*)&stage[((ks*4+lg)*32 + r15)*8];
          short8 b1 = *(const short8*)&stage[((ks*4+lg)*32 + 16 + r15)*8];
          acc[0][0] = MFMA(a[0][ks], b0, acc[0][0]);
          acc[1][0] = MFMA(a[1][ks], b0, acc[1][0]);
          acc[0][1] = MFMA(a[0][ks], b1, acc[0][1]);
          acc[1][1] = MFMA(a[1][ks], b1, acc[1][1]);
        }
      }
      float hn[2][2];
#pragma unroll
      for (int mi=0; mi<2; ++mi)
#pragma unroll
        for (int nj=0; nj<2; ++nj){
          float iv = sigm(acc[mi][nj][0]);
          float fv = sigm(acc[mi][nj][1]);
          float gv = tanh_(acc[mi][nj][2]);
          float ov = sigm(acc[mi][nj][3]);
          float cn = fv*c[mi][nj] + iv*gv;
          c[mi][nj] = cn;
          hn[mi][nj] = ov*tanh_(cn);
        }
      unsigned short* dst = Hx + ((long)(t&1)*16 + m)*32*256;
#pragma unroll
      for (int nj=0; nj<2; ++nj){
        unsigned int pk = (unsigned int)f2bf(hn[0][nj]) | ((unsigned int)f2bf(hn[1][nj]) << 16);
        __hip_atomic_store((unsigned int*)(dst + (long)(nj*16 + r15)*256 + hu0), pk,
                           __ATOMIC_RELAXED, __HIP_MEMORY_SCOPE_AGENT);
      }
    } else if (t > 0){
      // y_{t-1} = W_dec @ h^(t) + b_dec
      f32x4 yacc[2] = {ybias, ybias};
#pragma unroll
      for (int ks=0; ks<8; ++ks){
        short8 b0 = *(const short8*)&stage[((ks*4+lg)*32 + r15)*8];
        short8 b1 = *(const short8*)&stage[((ks*4+lg)*32 + 16 + r15)*8];
        yacc[0] = MFMA(ad[ks], b0, yacc[0]);
        yacc[1] = MFMA(ad[ks], b1, yacc[1]);
      }
#pragma unroll
      for (int nj=0; nj<2; ++nj)
        *(f32x4*)(out + ((long)(mbase + nj*16 + r15)*256 + (t-1))*128 + q*16 + lg*4) = yacc[nj];
    }
    __syncthreads();                               // D3: drain publishes
    if (tid == 0)
      __hip_atomic_fetch_add(flg + t, 1, __ATOMIC_RELEASE, __HIP_MEMORY_SCOPE_AGENT);
  }
  // epilogue: y_255 from h^(256)
  if (tid == 0){
    while (__hip_atomic_load(flg + 255, __ATOMIC_RELAXED, __HIP_MEMORY_SCOPE_AGENT) < 8)
      __builtin_amdgcn_s_sleep(1);
    __threadfence();
  }
  __syncthreads();
  if (tid < 256){
    const unsigned short* hsrc = Hx + ((long)1*16 + m)*32*256;   // buf (256-1)&1 = 1
#pragma unroll
    for (int j=0;j<4;j++)
      hreg[j] = *(const short8*)(hsrc + (long)sb*256 + (sk + j*8)*8);
#pragma unroll
    for (int j=0;j<4;j++)
      *(short8*)&stage[((sk + j*8)*32 + sb)*8] = hreg[j];
  }
  __syncthreads();
  if (w == 4){
    f32x4 yacc[2] = {ybias, ybias};
#pragma unroll
    for (int ks=0; ks<8; ++ks){
      short8 b0 = *(const short8*)&stage[((ks*4+lg)*32 + r15)*8];
      short8 b1 = *(const short8*)&stage[((ks*4+lg)*32 + 16 + r15)*8];
      yacc[0] = MFMA(ad[ks], b0, yacc[0]);
      yacc[1] = MFMA(ad[ks], b1, yacc[1]);
    }
#pragma unroll
    for (int nj=0; nj<2; ++nj)
      *(f32x4*)(out + ((long)(mbase + nj*16 + r15)*256 + 255)*128 + q*16 + lg*4) = yacc[nj];
  }
}

// ---------------- launch ----------------
extern "C" void kernel_launch(void* const* d_in, const int* in_sizes, int n_in,
                              void* d_out, int out_size, void* d_ws, size_t ws_size,
                              hipStream_t stream)
{
  const float* x    = (const float*)d_in[0];
  const float* eps  = (const float*)d_in[1];
  const float* Wie  = (const float*)d_in[2];
  const float* bie  = (const float*)d_in[3];
  const float* gamma= (const float*)d_in[4];
  const float* beta = (const float*)d_in[5];
  const float* Wihf = (const float*)d_in[6];
  const float* Whhf = (const float*)d_in[7];
  const float* bf_  = (const float*)d_in[8];
  const float* Wihb = (const float*)d_in[9];
  const float* Whhb = (const float*)d_in[10];
  const float* bb_  = (const float*)d_in[11];
  const float* Wmu  = (const float*)d_in[12];
  const float* bmu  = (const float*)d_in[13];
  const float* Wlv  = (const float*)d_in[14];
  const float* blv  = (const float*)d_in[15];
  const float* Wihd = (const float*)d_in[16];
  const float* Whhd = (const float*)d_in[17];
  const float* bd   = (const float*)d_in[18];
  const float* Wdec = (const float*)d_in[19];
  const float* bdec = (const float*)d_in[20];
  const float* Wso  = (const float*)d_in[21];
  const float* bso  = (const float*)d_in[22];

  float* z    = (float*)d_out;
  float* mu   = z + 131072;
  float* stdo = mu + 131072;
  float* so   = stdo + 131072;
  float* outp = so + 32768;

  unsigned char* cur = (unsigned char*)d_ws;
  auto take = [&](size_t bytes)->void*{ void* p = cur; cur += (bytes + 255) & ~(size_t)255; return p; };
  // contiguous zero range: bn + flgE + flgD
  float* bn   = (float*)take(512*4);             // 2048 B
  int* flgE   = (int*)take(2*16*256*4);          // 32768 B
  int* flgD   = (int*)take(16*256*4);            // 16384 B
  float* ab   = (float*)take(512*4);
  float* hF   = (float*)take(131072*4);
  float* cF   = (float*)take(131072*4);
  float* hB   = (float*)take(131072*4);
  float* cB   = (float*)take(131072*4);
  float* c0   = (float*)take(131072*4);
  float* benc = (float*)take(2048*4);
  float* biasd= (float*)take(1024*4);
  unsigned short* Wie_b = (unsigned short*)take(32768UL*2);
  unsigned short* Wenc  = (unsigned short*)take(2UL*1024*512*2);
  unsigned short* Wsum  = (unsigned short*)take(1024UL*256*2);
  unsigned short* W0r   = (unsigned short*)take(1024UL*256*2);
  unsigned short* Wdecb = (unsigned short*)take(128UL*256*2);
  float* pre0 = (float*)take(512UL*1024*4);
  unsigned short* HxE = (unsigned short*)take(2UL*2*16*32*256*2);
  unsigned short* HxD = (unsigned short*)take(2UL*16*32*256*2);
  unsigned short* h_b   = (unsigned short*)take(33554432UL*2);
  unsigned short* seq_b = (unsigned short*)take(33554432UL*2);

  k_memz<<<50, 256, 0, stream>>>((int*)bn, 12800);
  k_cvt4<<<32, 256, 0, stream>>>(Wie, Wie_b, 8192L);
  k_prepenc<<<1024, 256, 0, stream>>>(Wihf, Whhf, bf_, Wihb, Whhb, bb_, Wenc, benc);
  k_prepdec<<<512, 256, 0, stream>>>(Wihd, Whhd, bd, Wdec, Wsum, W0r, biasd, Wdecb);
  // h_b = x @ Wie^T + bie  (bf16, [B,T,H])
  k_gemmA32<<<dim3(2, 1024), 256, 0, stream>>>(x, Wie_b, (void*)h_b, bie, 131072, 256, 128, 0);
  k_bnstats<<<256, 256, 0, stream>>>(h_b, bn);
  k_bnab<<<1, 256, 0, stream>>>(bn, gamma, beta, ab);
  k_bnapply<<<2048, 256, 0, stream>>>(h_b, ab, seq_b);
  k_enc<<<256, 256, 0, stream>>>(seq_b, Wenc, benc, HxE, flgE, hF, cF, hB, cB);
  k_mid<<<512, 256, 0, stream>>>(hF, cF, hB, cB, eps, Wmu, bmu, Wlv, blv, Wso, bso, z, mu, stdo, so, c0);
  // pre0 = z @ Whh_d^T + b_d  (fp32, permuted gate rows)
  k_gemmA32<<<dim3(8, 4), 256, 0, stream>>>(z, W0r, (void*)pre0, biasd, 512, 1024, 256, 1);
  k_dec<<<128, 320, 0, stream>>>(Wsum, Wdecb, biasd, bdec, pre0, c0, HxD, flgD, outp);
}

// Round 4
// 2442.384 us; speedup vs baseline: 2.4444x; 2.4444x over previous
//
#include <hip/hip_runtime.h>
#include <stdint.h>

// LSTM-VAE for MI355X (gfx950).  B=512, T=256, CIN=128, H=256, COUT=64.
//
// Round-2 -> Round-3 change (surgical): remove ALL per-step cache-coherence
// ops from the persistent recurrence kernels.
//  - r2 used __threadfence() acquire (= buffer_inv, full L2 invalidate) and
//    RELEASE atomics (= buffer_wbl2, full L2 writeback) EVERY step on EVERY
//    CU -> FETCH_SIZE 1.05GB (x tiles refetched each step), 15.5us/step.
//  - Now: flags and h-exchange data are RELAXED AGENT-scope atomics (sc0/sc1
//    -> operate at the device coherence point, bypass stale L2, no inv/wb).
//    Ordering: __syncthreads() drains vmcnt(0) before the flag add is issued.
//  - h publishes are packed via a padded LDS transpose into one contiguous
//    2KB block per WG (coalesced 8B atomic stores), readers gather 8 blocks.
// Everything else (weights-in-registers gate-split structure, GEMMs, BN,
// latent head) is identical to the r2 kernel that passed validation.
// (Resubmitted unchanged after r3 GPU-acquisition timeout.)

typedef __attribute__((ext_vector_type(8)))  short  short8;
typedef __attribute__((ext_vector_type(4)))  float  f32x4;
typedef __attribute__((ext_vector_type(2)))  float  f32x2;
typedef __attribute__((ext_vector_type(4)))  unsigned short u16x4;

static __device__ __forceinline__ float bf2f(unsigned short u){
  union{unsigned int i; float f;} v; v.i = ((unsigned int)u)<<16; return v.f;
}
static __device__ __forceinline__ unsigned short f2bf(float f){
  union{float f; unsigned int i;} v; v.f=f;
  return (unsigned short)((v.i + 0x7fffu + ((v.i>>16)&1u))>>16);
}
static __device__ __forceinline__ float sigm(float x){ return 1.f/(1.f+__expf(-x)); }
static __device__ __forceinline__ float tanh_(float x){ return 2.f/(1.f+__expf(-2.f*x)) - 1.f; }

#define MFMA(a,b,c) __builtin_amdgcn_mfma_f32_16x16x32_bf16((a),(b),(c),0,0,0)

// gate-row permutation: n' = s*32 + mi*16 + lg*4 + g  with hu = s*8 + lg*2 + mi
static __device__ __forceinline__ int permn(int np){
  int s = np>>5, mi = (np>>4)&1, lg = (np>>2)&3, g = np&3;
  int hu = s*8 + lg*2 + mi;
  return g*256 + hu;
}

// ---------------- tiny prep kernels ----------------

__global__ void k_memz(int* p, int n){
  int i = blockIdx.x*blockDim.x + threadIdx.x;
  if (i < n) p[i] = 0;
}

__global__ void k_cvt4(const float* __restrict__ s, unsigned short* __restrict__ d, long n4){
  for (long i = (long)blockIdx.x*blockDim.x + threadIdx.x; i < n4; i += (long)gridDim.x*blockDim.x){
    f32x4 v = *(const f32x4*)(s + i*4);
    u16x4 u; u[0]=f2bf(v[0]); u[1]=f2bf(v[1]); u[2]=f2bf(v[2]); u[3]=f2bf(v[3]);
    *(u16x4*)(d + i*4) = u;
  }
}

__global__ void k_prepenc(const float* __restrict__ Wihf, const float* __restrict__ Whhf,
                          const float* __restrict__ bf_,
                          const float* __restrict__ Wihb, const float* __restrict__ Whhb,
                          const float* __restrict__ bb_,
                          unsigned short* __restrict__ Wenc, float* __restrict__ benc){
  for (long i = (long)blockIdx.x*blockDim.x + threadIdx.x; i < 2L*1024*512; i += (long)gridDim.x*blockDim.x){
    int k  = (int)(i & 511);
    int np = (int)((i >> 9) & 1023);
    int ch = (int)(i >> 19);
    int n  = permn(np);
    const float* Wih = ch ? Wihb : Wihf;
    const float* Whh = ch ? Whhb : Whhf;
    float v = (k < 256) ? Wih[n*256 + k] : Whh[n*256 + (k-256)];
    Wenc[i] = f2bf(v);
    if (k == 0) benc[ch*1024 + np] = ch ? bb_[n] : bf_[n];
  }
}

__global__ void k_prepdec(const float* __restrict__ Wihd, const float* __restrict__ Whhd,
                          const float* __restrict__ bd, const float* __restrict__ Wdec,
                          unsigned short* __restrict__ Wsum, unsigned short* __restrict__ W0r,
                          float* __restrict__ biasd, unsigned short* __restrict__ Wdecb){
  const long N1 = 1024L*256;
  for (long i = (long)blockIdx.x*blockDim.x + threadIdx.x; i < N1 + 128L*256; i += (long)gridDim.x*blockDim.x){
    if (i < N1){
      int k = (int)(i & 255), np = (int)(i >> 8);
      int n = permn(np);
      float wh = Whhd[n*256 + k];
      Wsum[i] = f2bf(Wihd[n*256 + k] + wh);
      W0r[i]  = f2bf(wh);
      if (k == 0) biasd[np] = bd[n];
    } else {
      long j = i - N1;
      Wdecb[j] = f2bf(Wdec[j]);
    }
  }
}

// ---------------- GEMM: C[M,N] = A_f32[M,K] @ Bt_bf16[N,K]^T + bias ----------------
__global__ __launch_bounds__(256, 2) void k_gemmA32(
    const float* __restrict__ A, const unsigned short* __restrict__ Bt,
    void* __restrict__ Cout, const float* __restrict__ bias,
    int M, int N, int K, int outf32)
{
  __shared__ unsigned short As[128*64];
  __shared__ unsigned short Bs[128*64];
  const int tid = threadIdx.x, lane = tid & 63, wid = tid >> 6;
  const int lg = lane >> 4, r15 = lane & 15;
  const long mbase = (long)blockIdx.y * 128;
  const long nbase = (long)blockIdx.x * 128;
  f32x4 acc[4][4];
#pragma unroll
  for (int i=0;i<4;i++)
#pragma unroll
    for (int j=0;j<4;j++) acc[i][j] = (f32x4)(0.f);
  const int wrow = (wid>>1)*64, wcol = (wid&1)*64;

  for (int kc = 0; kc < K; kc += 64){
    {
      const int col4 = (tid&15)*4, rowb = tid>>4;
#pragma unroll
      for (int i=0;i<8;i++){
        int row = rowb + 16*i;
        f32x4 v = *(const f32x4*)(A + (mbase+row)*(long)K + kc + col4);
        u16x4 u; u[0]=f2bf(v[0]); u[1]=f2bf(v[1]); u[2]=f2bf(v[2]); u[3]=f2bf(v[3]);
        int byte = row*128 + ((col4*2) ^ ((row&7)<<4));
        *(u16x4*)((char*)As + byte) = u;
      }
      const int kq = tid&7, rowb2 = tid>>3;
#pragma unroll
      for (int i=0;i<4;i++){
        int row = rowb2 + 32*i;
        short8 v = *(const short8*)(Bt + (nbase+row)*(long)K + kc + kq*8);
        int byte = row*128 + ((kq*16) ^ ((row&7)<<4));
        *(short8*)((char*)Bs + byte) = v;
      }
    }
    __syncthreads();
#pragma unroll
    for (int ks=0; ks<2; ++ks){
      short8 a[4], b[4];
#pragma unroll
      for (int mi=0; mi<4; ++mi){
        int row = wrow + mi*16 + r15;
        int byte = row*128 + ((ks*64 + lg*16) ^ ((row&7)<<4));
        a[mi] = *(const short8*)((char*)As + byte);
      }
#pragma unroll
      for (int ni=0; ni<4; ++ni){
        int row = wcol + ni*16 + r15;
        int byte = row*128 + ((ks*64 + lg*16) ^ ((row&7)<<4));
        b[ni] = *(const short8*)((char*)Bs + byte);
      }
#pragma unroll
      for (int mi=0; mi<4; ++mi)
#pragma unroll
        for (int ni=0; ni<4; ++ni)
          acc[mi][ni] = MFMA(a[mi], b[ni], acc[mi][ni]);
    }
    __syncthreads();
  }
#pragma unroll
  for (int ni=0; ni<4; ++ni){
    long col = nbase + wcol + ni*16 + r15;
    float bv = bias[col];
#pragma unroll
    for (int mi=0; mi<4; ++mi)
#pragma unroll
      for (int rr=0; rr<4; ++rr){
        long row = mbase + wrow + mi*16 + lg*4 + rr;
        float val = acc[mi][ni][rr] + bv;
        if (outf32) ((float*)Cout)[row*N + col] = val;
        else        ((unsigned short*)Cout)[row*N + col] = f2bf(val);
      }
  }
}

// ---------------- BatchNorm ----------------

__global__ void k_bnstats(const unsigned short* __restrict__ hb, float* __restrict__ bn){
  __shared__ float sred[8][256];
  __shared__ float qred[8][256];
  const int tid = threadIdx.x, kq = tid&31, rw = tid>>5;
  float s[8], qq[8];
#pragma unroll
  for (int j=0;j<8;j++){ s[j]=0.f; qq[j]=0.f; }
  const long base = (long)blockIdx.x * 512;
  for (int i=0;i<64;i++){
    long row = base + rw + 8L*i;
    short8 v = *(const short8*)(hb + row*256 + kq*8);
#pragma unroll
    for (int j=0;j<8;j++){ float f = bf2f(((unsigned short*)&v)[j]); s[j]+=f; qq[j]+=f*f; }
  }
#pragma unroll
  for (int j=0;j<8;j++){ sred[rw][kq*8+j]=s[j]; qred[rw][kq*8+j]=qq[j]; }
  __syncthreads();
  if (tid < 256){
    float ts=0.f, tq=0.f;
#pragma unroll
    for (int r=0;r<8;r++){ ts += sred[r][tid]; tq += qred[r][tid]; }
    atomicAdd(&bn[tid], ts);
    atomicAdd(&bn[256+tid], tq);
  }
}

__global__ void k_bnab(const float* __restrict__ bn, const float* __restrict__ gamma,
                       const float* __restrict__ beta, float* __restrict__ ab){
  const int j = threadIdx.x;
  const float mean = bn[j] * (1.f/131072.f);
  const float var  = bn[256+j] * (1.f/131072.f) - mean*mean;
  const float a = gamma[j] * rsqrtf(var + 1e-5f);
  ab[j] = a;
  ab[256+j] = beta[j] - mean*a;
}

__global__ void k_bnapply(const unsigned short* __restrict__ hb, const float* __restrict__ ab,
                          unsigned short* __restrict__ seq){
  const int tid = threadIdx.x, kq = tid&31, ro = tid>>5;
  float av[8], bv[8];
#pragma unroll
  for (int j=0;j<8;j++){ av[j]=ab[kq*8+j]; bv[j]=ab[256+kq*8+j]; }
  const long r0 = (long)blockIdx.x * 64;
  for (int i=0;i<8;i++){
    long row = r0 + ro + 8L*i;
    short8 v = *(const short8*)(hb + row*256 + kq*8);
    short8 u;
#pragma unroll
    for (int j=0;j<8;j++){
      float f = bf2f(((unsigned short*)&v)[j])*av[j] + bv[j];
      f = f > 0.f ? f : 0.2f*f;
      ((unsigned short*)&u)[j] = f2bf(f);
    }
    long b = row >> 8, t = row & 255;
    *(short8*)(seq + (t*512 + b)*256 + kq*8) = u;
  }
}

// ---------------- encoder recurrence ----------------
// 256 WGs x 256 thr. WG=(chain, m-tile of 32 batch, q gate slice of 128 rows).
// Weight A-fragments resident in registers. h exchanged via RELAXED agent
// atomics, packed 2KB blocks; no fences anywhere in the step loop.
__global__ __launch_bounds__(256, 1) void k_enc(
    const unsigned short* __restrict__ seqb, const unsigned short* __restrict__ Wenc,
    const float* __restrict__ benc, unsigned short* __restrict__ Hx,
    int* __restrict__ flags, float* __restrict__ hF, float* __restrict__ cF,
    float* __restrict__ hB, float* __restrict__ cB)
{
  __shared__ unsigned short stage[49152];              // 96KB -> 1 WG/CU (co-residency)
  unsigned int* tpose = (unsigned int*)&stage[16384];  // [32 b][17] dwords (padded)
  const int tid = threadIdx.x, lane = tid & 63, w = tid >> 6;
  const int lg = (lane>>4)&3, r15 = lane & 15;
  const int chain = blockIdx.x>>7, m = (blockIdx.x>>3)&15, q = blockIdx.x&7;
  const int mbase = m*32;

  const unsigned short* Wp = Wenc + ((long)chain*1024 + q*128 + w*32)*512;
  short8 a[2][16];
#pragma unroll
  for (int mi=0; mi<2; ++mi)
#pragma unroll
    for (int ks=0; ks<16; ++ks)
      a[mi][ks] = *(const short8*)(Wp + (long)(mi*16 + r15)*512 + ks*32 + lg*8);
  f32x4 bias[2];
#pragma unroll
  for (int mi=0; mi<2; ++mi)
    bias[mi] = *(const f32x4*)(benc + chain*1024 + q*128 + w*32 + mi*16 + lg*4);

  float c[2][2];
  c[0][0]=0.f; c[0][1]=0.f; c[1][0]=0.f; c[1][1]=0.f;
  float* hOut = chain ? hB : hF;
  float* cOut = chain ? cB : cF;
  int* flg = flags + (chain*16 + m)*256;
  unsigned short* HxC = Hx + (long)chain*(2*16*8*1024);
  const int sb = tid&31, sk = tid>>5;
  const int hu0 = (q*4 + w)*8 + lg*2;
  const int gb = tid>>3, gh = tid&7;                   // gather/publish coords

  short8 xreg[4];
  {
    long trow = chain ? 255 : 0;
#pragma unroll
    for (int j=0;j<4;j++)
      xreg[j] = *(const short8*)(seqb + (trow*512 + mbase + sb)*256 + (sk + j*8)*8);
  }

  for (int t=0; t<256; ++t){
    // stage x_t (k-chunks 0..31)
#pragma unroll
    for (int j=0;j<4;j++)
      *(short8*)&stage[((sk + j*8)*32 + sb)*8] = xreg[j];
    __syncthreads();                               // B1
    if (t < 255){
      long trow = chain ? (long)(254 - t) : (long)(t + 1);
#pragma unroll
      for (int j=0;j<4;j++)
        xreg[j] = *(const short8*)(seqb + (trow*512 + mbase + sb)*256 + (sk + j*8)*8);
    }
    // x-part MFMAs first (independent of other WGs -> hides partner skew)
    f32x4 acc[2][2];
    acc[0][0]=bias[0]; acc[0][1]=bias[0]; acc[1][0]=bias[1]; acc[1][1]=bias[1];
#pragma unroll
    for (int ks=0; ks<8; ++ks){
      short8 b0 = *(const short8*)&stage[((ks*4+lg)*32 + r15)*8];
      short8 b1 = *(const short8*)&stage[((ks*4+lg)*32 + 16 + r15)*8];
      acc[0][0] = MFMA(a[0][ks], b0, acc[0][0]);
      acc[1][0] = MFMA(a[1][ks], b0, acc[1][0]);
      acc[0][1] = MFMA(a[0][ks], b1, acc[0][1]);
      acc[1][1] = MFMA(a[1][ks], b1, acc[1][1]);
    }
    if (t > 0){
      if (tid == 0){
        while (__hip_atomic_load(flg + t - 1, __ATOMIC_RELAXED, __HIP_MEMORY_SCOPE_AGENT) < 8)
          __builtin_amdgcn_s_sleep(1);
      }
      __syncthreads();                             // B2
      unsigned long long* src = (unsigned long long*)(HxC + ((long)((t-1)&1)*16 + m)*8*1024);
#pragma unroll
      for (int qq=0; qq<8; ++qq){
        unsigned long long v = __hip_atomic_load(src + qq*256 + tid, __ATOMIC_RELAXED, __HIP_MEMORY_SCOPE_AGENT);
        *(unsigned long long*)&stage[((32 + qq*4 + (gh>>1))*32 + gb)*8 + (gh&1)*4] = v;
      }
      __syncthreads();                             // B3
#pragma unroll
      for (int ks=8; ks<16; ++ks){
        short8 b0 = *(const short8*)&stage[((ks*4+lg)*32 + r15)*8];
        short8 b1 = *(const short8*)&stage[((ks*4+lg)*32 + 16 + r15)*8];
        acc[0][0] = MFMA(a[0][ks], b0, acc[0][0]);
        acc[1][0] = MFMA(a[1][ks], b0, acc[1][0]);
        acc[0][1] = MFMA(a[0][ks], b1, acc[0][1]);
        acc[1][1] = MFMA(a[1][ks], b1, acc[1][1]);
      }
    }
    float hn[2][2];
#pragma unroll
    for (int mi=0; mi<2; ++mi)
#pragma unroll
      for (int nj=0; nj<2; ++nj){
        float iv = sigm(acc[mi][nj][0]);
        float fv = sigm(acc[mi][nj][1]);
        float gv = tanh_(acc[mi][nj][2]);
        float ov = sigm(acc[mi][nj][3]);
        float cn = fv*c[mi][nj] + iv*gv;
        c[mi][nj] = cn;
        hn[mi][nj] = ov*tanh_(cn);
      }
    if (t < 255){
      // transpose h slice in LDS -> one contiguous 2KB packed block
#pragma unroll
      for (int nj=0; nj<2; ++nj)
        tpose[(nj*16 + r15)*17 + w*4 + lg] =
          (unsigned int)f2bf(hn[0][nj]) | ((unsigned int)f2bf(hn[1][nj]) << 16);
      __syncthreads();                             // B4
      {
        unsigned int lo = tpose[gb*17 + gh*2];
        unsigned int hi = tpose[gb*17 + gh*2 + 1];
        unsigned long long v = (unsigned long long)lo | ((unsigned long long)hi << 32);
        unsigned long long* dst = (unsigned long long*)(HxC + (((long)(t&1)*16 + m)*8 + q)*1024);
        __hip_atomic_store(dst + tid, v, __ATOMIC_RELAXED, __HIP_MEMORY_SCOPE_AGENT);
      }
      __syncthreads();                             // B5: vmcnt(0) drained for all threads
      if (tid == 0)
        __hip_atomic_fetch_add(flg + t, 1, __ATOMIC_RELAXED, __HIP_MEMORY_SCOPE_AGENT);
    } else {
#pragma unroll
      for (int nj=0; nj<2; ++nj){
        long b = mbase + nj*16 + r15;
        f32x2 hv; hv[0]=hn[0][nj]; hv[1]=hn[1][nj];
        f32x2 cv; cv[0]=c[0][nj];  cv[1]=c[1][nj];
        *(f32x2*)(hOut + b*256 + hu0) = hv;
        *(f32x2*)(cOut + b*256 + hu0) = cv;
      }
    }
  }
}

// ---------------- latent head ----------------
__global__ void k_mid(
    const float* __restrict__ hF, const float* __restrict__ cF,
    const float* __restrict__ hB, const float* __restrict__ cB,
    const float* __restrict__ eps,
    const float* __restrict__ Wmu, const float* __restrict__ bmu,
    const float* __restrict__ Wlv, const float* __restrict__ blv,
    const float* __restrict__ Wso, const float* __restrict__ bso,
    float* __restrict__ z, float* __restrict__ mu, float* __restrict__ stdo,
    float* __restrict__ so, float* __restrict__ c0)
{
  __shared__ float code[256];
  __shared__ float zsh[256];
  const int b = blockIdx.x, j = threadIdx.x;
  const long o = (long)b*256 + j;
  code[j] = hF[o] + hB[o];
  c0[o] = cF[o] + cB[o];
  __syncthreads();
  float sm = bmu[j], sl = blv[j];
  for (int k=0;k<256;k++){
    float cv = code[k];
    sm += cv * Wmu[j*256 + k];
    sl += cv * Wlv[j*256 + k];
  }
  float st = __expf(0.5f*sl);
  float zz = sm + st*eps[o];
  mu[o]=sm; stdo[o]=st; z[o]=zz;
  zsh[j]=zz;
  __syncthreads();
  if (j < 64){
    float s = bso[j];
    for (int k=0;k<256;k++) s += zsh[k]*Wso[j*256 + k];
    so[(long)b*64 + j] = s;
  }
}

// ---------------- decoder recurrence ----------------
// 128 WGs x 320 thr (4 gate waves + 1 y wave). Same relaxed-atomic exchange.
__global__ __launch_bounds__(320, 1) void k_dec(
    const unsigned short* __restrict__ Wsum, const unsigned short* __restrict__ Wdecb,
    const float* __restrict__ biasd, const float* __restrict__ bdec,
    const float* __restrict__ pre0, const float* __restrict__ c0,
    unsigned short* __restrict__ Hx, int* __restrict__ flags, float* __restrict__ out)
{
  __shared__ unsigned short stage[49152];             // 96KB -> 1 WG/CU
  unsigned int* tpose = (unsigned int*)&stage[8192];  // [32 b][17] dwords
  const int tid = threadIdx.x, lane = tid & 63, w = tid >> 6;
  const int lg = (lane>>4)&3, r15 = lane & 15;
  const int m = blockIdx.x>>3, q = blockIdx.x&7, mbase = m*32;
  int* flg = flags + m*256;
  const int sb = tid&31, sk = tid>>5; (void)sb; (void)sk;
  const int gb = tid>>3, gh = tid&7;
  const int hu0 = (q*4 + w)*8 + lg*2;

  short8 a[2][8];
  f32x4 bias[2];
  float c[2][2];
  short8 ad[8];
  f32x4 ybias;
  if (w < 4){
    const unsigned short* Wp = Wsum + (long)(q*128 + w*32)*256;
#pragma unroll
    for (int mi=0; mi<2; ++mi)
#pragma unroll
      for (int ks=0; ks<8; ++ks)
        a[mi][ks] = *(const short8*)(Wp + (long)(mi*16 + r15)*256 + ks*32 + lg*8);
#pragma unroll
    for (int mi=0; mi<2; ++mi)
      bias[mi] = *(const f32x4*)(biasd + q*128 + w*32 + mi*16 + lg*4);
#pragma unroll
    for (int nj=0; nj<2; ++nj){
      f32x2 cc = *(const f32x2*)(c0 + (long)(mbase + nj*16 + r15)*256 + hu0);
      c[0][nj]=cc[0]; c[1][nj]=cc[1];
    }
  } else {
#pragma unroll
    for (int ks=0; ks<8; ++ks)
      ad[ks] = *(const short8*)(Wdecb + (long)(q*16 + r15)*256 + ks*32 + lg*8);
    ybias = *(const f32x4*)(bdec + q*16 + lg*4);
  }

  for (int t=0; t<256; ++t){
    if (t > 0){
      if (tid == 0){
        while (__hip_atomic_load(flg + t - 1, __ATOMIC_RELAXED, __HIP_MEMORY_SCOPE_AGENT) < 8)
          __builtin_amdgcn_s_sleep(1);
      }
      __syncthreads();                             // D1
      if (tid < 256){
        unsigned long long* src = (unsigned long long*)(Hx + ((long)((t-1)&1)*16 + m)*8*1024);
#pragma unroll
        for (int qq=0; qq<8; ++qq){
          unsigned long long v = __hip_atomic_load(src + qq*256 + tid, __ATOMIC_RELAXED, __HIP_MEMORY_SCOPE_AGENT);
          *(unsigned long long*)&stage[((qq*4 + (gh>>1))*32 + gb)*8 + (gh&1)*4] = v;
        }
      }
      __syncthreads();                             // D2: h^(t) staged
    }
    if (w < 4){
      f32x4 acc[2][2];
      if (t == 0){
#pragma unroll
        for (int mi=0; mi<2; ++mi)
#pragma unroll
          for (int nj=0; nj<2; ++nj)
            acc[mi][nj] = *(const f32x4*)(pre0 + (long)(mbase + nj*16 + r15)*1024 + q*128 + w*32 + mi*16 + lg*4);
      } else {
        acc[0][0]=bias[0]; acc[0][1]=bias[0]; acc[1][0]=bias[1]; acc[1][1]=bias[1];
#pragma unroll
        for (int ks=0; ks<8; ++ks){
          short8 b0 = *(const short8*)&stage[((ks*4+lg)*32 + r15)*8];
          short8 b1 = *(const short8*)&stage[((ks*4+lg)*32 + 16 + r15)*8];
          acc[0][0] = MFMA(a[0][ks], b0, acc[0][0]);
          acc[1][0] = MFMA(a[1][ks], b0, acc[1][0]);
          acc[0][1] = MFMA(a[0][ks], b1, acc[0][1]);
          acc[1][1] = MFMA(a[1][ks], b1, acc[1][1]);
        }
      }
      float hn[2][2];
#pragma unroll
      for (int mi=0; mi<2; ++mi)
#pragma unroll
        for (int nj=0; nj<2; ++nj){
          float iv = sigm(acc[mi][nj][0]);
          float fv = sigm(acc[mi][nj][1]);
          float gv = tanh_(acc[mi][nj][2]);
          float ov = sigm(acc[mi][nj][3]);
          float cn = fv*c[mi][nj] + iv*gv;
          c[mi][nj] = cn;
          hn[mi][nj] = ov*tanh_(cn);
        }
#pragma unroll
      for (int nj=0; nj<2; ++nj)
        tpose[(nj*16 + r15)*17 + w*4 + lg] =
          (unsigned int)f2bf(hn[0][nj]) | ((unsigned int)f2bf(hn[1][nj]) << 16);
    } else if (t > 0){
      // y_{t-1} = W_dec @ h^(t) + b_dec
      f32x4 yacc[2] = {ybias, ybias};
#pragma unroll
      for (int ks=0; ks<8; ++ks){
        short8 b0 = *(const short8*)&stage[((ks*4+lg)*32 + r15)*8];
        short8 b1 = *(const short8*)&stage[((ks*4+lg)*32 + 16 + r15)*8];
        yacc[0] = MFMA(ad[ks], b0, yacc[0]);
        yacc[1] = MFMA(ad[ks], b1, yacc[1]);
      }
#pragma unroll
      for (int nj=0; nj<2; ++nj)
        *(f32x4*)(out + ((long)(mbase + nj*16 + r15)*256 + (t-1))*128 + q*16 + lg*4) = yacc[nj];
    }
    __syncthreads();                               // D3: tpose ready, stage reads done
    if (tid < 256){
      unsigned int lo = tpose[gb*17 + gh*2];
      unsigned int hi = tpose[gb*17 + gh*2 + 1];
      unsigned long long v = (unsigned long long)lo | ((unsigned long long)hi << 32);
      unsigned long long* dst = (unsigned long long*)(Hx + (((long)(t&1)*16 + m)*8 + q)*1024);
      __hip_atomic_store(dst + tid, v, __ATOMIC_RELAXED, __HIP_MEMORY_SCOPE_AGENT);
    }
    __syncthreads();                               // D4: drained
    if (tid == 0)
      __hip_atomic_fetch_add(flg + t, 1, __ATOMIC_RELAXED, __HIP_MEMORY_SCOPE_AGENT);
  }
  // epilogue: y_255 from h^(256) (published at t=255, buf 1)
  if (tid == 0){
    while (__hip_atomic_load(flg + 255, __ATOMIC_RELAXED, __HIP_MEMORY_SCOPE_AGENT) < 8)
      __builtin_amdgcn_s_sleep(1);
  }
  __syncthreads();
  if (tid < 256){
    unsigned long long* src = (unsigned long long*)(Hx + ((long)1*16 + m)*8*1024);
#pragma unroll
    for (int qq=0; qq<8; ++qq){
      unsigned long long v = __hip_atomic_load(src + qq*256 + tid, __ATOMIC_RELAXED, __HIP_MEMORY_SCOPE_AGENT);
      *(unsigned long long*)&stage[((qq*4 + (gh>>1))*32 + gb)*8 + (gh&1)*4] = v;
    }
  }
  __syncthreads();
  if (w == 4){
    f32x4 yacc[2] = {ybias, ybias};
#pragma unroll
    for (int ks=0; ks<8; ++ks){
      short8 b0 = *(const short8*)&stage[((ks*4+lg)*32 + r15)*8];
      short8 b1 = *(const short8*)&stage[((ks*4+lg)*32 + 16 + r15)*8];
      yacc[0] = MFMA(ad[ks], b0, yacc[0]);
      yacc[1] = MFMA(ad[ks], b1, yacc[1]);
    }
#pragma unroll
    for (int nj=0; nj<2; ++nj)
      *(f32x4*)(out + ((long)(mbase + nj*16 + r15)*256 + 255)*128 + q*16 + lg*4) = yacc[nj];
  }
}

// ---------------- launch ----------------
extern "C" void kernel_launch(void* const* d_in, const int* in_sizes, int n_in,
                              void* d_out, int out_size, void* d_ws, size_t ws_size,
                              hipStream_t stream)
{
  const float* x    = (const float*)d_in[0];
  const float* eps  = (const float*)d_in[1];
  const float* Wie  = (const float*)d_in[2];
  const float* bie  = (const float*)d_in[3];
  const float* gamma= (const float*)d_in[4];
  const float* beta = (const float*)d_in[5];
  const float* Wihf = (const float*)d_in[6];
  const float* Whhf = (const float*)d_in[7];
  const float* bf_  = (const float*)d_in[8];
  const float* Wihb = (const float*)d_in[9];
  const float* Whhb = (const float*)d_in[10];
  const float* bb_  = (const float*)d_in[11];
  const float* Wmu  = (const float*)d_in[12];
  const float* bmu  = (const float*)d_in[13];
  const float* Wlv  = (const float*)d_in[14];
  const float* blv  = (const float*)d_in[15];
  const float* Wihd = (const float*)d_in[16];
  const float* Whhd = (const float*)d_in[17];
  const float* bd   = (const float*)d_in[18];
  const float* Wdec = (const float*)d_in[19];
  const float* bdec = (const float*)d_in[20];
  const float* Wso  = (const float*)d_in[21];
  const float* bso  = (const float*)d_in[22];

  float* z    = (float*)d_out;
  float* mu   = z + 131072;
  float* stdo = mu + 131072;
  float* so   = stdo + 131072;
  float* outp = so + 32768;

  unsigned char* cur = (unsigned char*)d_ws;
  auto take = [&](size_t bytes)->void*{ void* p = cur; cur += (bytes + 255) & ~(size_t)255; return p; };
  // contiguous zero range: bn + flgE + flgD
  float* bn   = (float*)take(512*4);
  int* flgE   = (int*)take(2*16*256*4);
  int* flgD   = (int*)take(16*256*4);
  float* ab   = (float*)take(512*4);
  float* hF   = (float*)take(131072*4);
  float* cF   = (float*)take(131072*4);
  float* hB   = (float*)take(131072*4);
  float* cB   = (float*)take(131072*4);
  float* c0   = (float*)take(131072*4);
  float* benc = (float*)take(2048*4);
  float* biasd= (float*)take(1024*4);
  unsigned short* Wie_b = (unsigned short*)take(32768UL*2);
  unsigned short* Wenc  = (unsigned short*)take(2UL*1024*512*2);
  unsigned short* Wsum  = (unsigned short*)take(1024UL*256*2);
  unsigned short* W0r   = (unsigned short*)take(1024UL*256*2);
  unsigned short* Wdecb = (unsigned short*)take(128UL*256*2);
  float* pre0 = (float*)take(512UL*1024*4);
  unsigned short* HxE = (unsigned short*)take(2UL*2*16*8*1024*2);
  unsigned short* HxD = (unsigned short*)take(2UL*16*8*1024*2);
  unsigned short* h_b   = (unsigned short*)take(33554432UL*2);
  unsigned short* seq_b = (unsigned short*)take(33554432UL*2);

  k_memz<<<50, 256, 0, stream>>>((int*)bn, 12800);
  k_cvt4<<<32, 256, 0, stream>>>(Wie, Wie_b, 8192L);
  k_prepenc<<<1024, 256, 0, stream>>>(Wihf, Whhf, bf_, Wihb, Whhb, bb_, Wenc, benc);
  k_prepdec<<<512, 256, 0, stream>>>(Wihd, Whhd, bd, Wdec, Wsum, W0r, biasd, Wdecb);
  // h_b = x @ Wie^T + bie  (bf16, [B,T,H])
  k_gemmA32<<<dim3(2, 1024), 256, 0, stream>>>(x, Wie_b, (void*)h_b, bie, 131072, 256, 128, 0);
  k_bnstats<<<256, 256, 0, stream>>>(h_b, bn);
  k_bnab<<<1, 256, 0, stream>>>(bn, gamma, beta, ab);
  k_bnapply<<<2048, 256, 0, stream>>>(h_b, ab, seq_b);
  k_enc<<<256, 256, 0, stream>>>(seq_b, Wenc, benc, HxE, flgE, hF, cF, hB, cB);
  k_mid<<<512, 256, 0, stream>>>(hF, cF, hB, cB, eps, Wmu, bmu, Wlv, blv, Wso, bso, z, mu, stdo, so, c0);
  // pre0 = z @ Whh_d^T + b_d  (fp32, permuted gate rows)
  k_gemmA32<<<dim3(8, 4), 256, 0, stream>>>(z, W0r, (void*)pre0, biasd, 512, 1024, 256, 1);
  k_dec<<<128, 320, 0, stream>>>(Wsum, Wdecb, biasd, bdec, pre0, c0, HxD, flgD, outp);
}